// Round 4
// baseline (58374.713 us; speedup 1.0000x reference)
//
#include <hip/hip_runtime.h>
#include <hip/hip_bf16.h>

#define SEQ_LEN 256
#define NB 64
#define NV 10000
#define ND 1024

__device__ __forceinline__ float sigf(float z) { return 1.f / (1.f + expf(-z)); }

__device__ __forceinline__ float dot8_f32(const float* hv, const float* wp, float acc) {
  float4 w0 = *(const float4*)wp;
  float4 w1 = *(const float4*)(wp + 4);
  acc += hv[0] * w0.x; acc += hv[1] * w0.y; acc += hv[2] * w0.z; acc += hv[3] * w0.w;
  acc += hv[4] * w1.x; acc += hv[5] * w1.y; acc += hv[6] * w1.z; acc += hv[7] * w1.w;
  return acc;
}

// ---- diagnostic flood (f32 out) ----
__global__ void floodk(float* out, float val, unsigned long long n) {
  unsigned long long i = (unsigned long long)blockIdx.x * 256 + threadIdx.x;
  if (i < n) out[i] = val;
}

// ---- init: transpose f32 states to feature-major [k][b] ----
__global__ void init_state(const float* __restrict__ h0, const float* __restrict__ c0,
                           float* __restrict__ hT, float* __restrict__ cT) {
  int i = blockIdx.x * 256 + threadIdx.x;   // 0..65535
  int k = i >> 6, b = i & 63;
  hT[i] = h0[b * ND + k];
  cT[i] = c0[b * ND + k];
}

// ---- mogrifier phase: out[c][b] = 2*sigmoid(sum_k act[k][b]*W[c][k] + bias[c]) * mult[c][b]
// block = 256 thr = 4 waves; 4 columns/block; wave = K-chunk of 256; lane = batch.
template<bool EMB>
__global__ __launch_bounds__(256) void mog_phase(
    const float* __restrict__ actT,   // 1024 x 64 feature-major
    const float* __restrict__ W,      // C x 1024 row-major
    const float* __restrict__ bias,   // C
    const float* __restrict__ multT,  // C x 64 (if !EMB)
    const float* __restrict__ emb,    // V x D  (if EMB)
    const int*   __restrict__ tok,    // B      (if EMB)
    float* __restrict__ outT)         // C x 64
{
  const int tid = threadIdx.x;
  const int wv = tid >> 6;
  const int lane = tid & 63;
  const int c0 = blockIdx.x * 4;
  __shared__ float red[4][4][64];

  float acc[4] = {0.f, 0.f, 0.f, 0.f};
  const int kb = wv * 256;
  const float* ap = actT + (size_t)kb * NB + lane;

  for (int k = 0; k < 256; k += 8) {
    float hv[8];
#pragma unroll
    for (int q = 0; q < 8; ++q) hv[q] = ap[(k + q) * NB];
#pragma unroll
    for (int c = 0; c < 4; ++c)
      acc[c] = dot8_f32(hv, W + (size_t)(c0 + c) * ND + kb + k, acc[c]);
  }
#pragma unroll
  for (int c = 0; c < 4; ++c) red[wv][c][lane] = acc[c];
  __syncthreads();

  const int c = tid >> 6, b = tid & 63;
  float z = red[0][c][b] + red[1][c][b] + red[2][c][b] + red[3][c][b];
  z += bias[c0 + c];
  float g = 2.f * sigf(z);
  float m;
  if (EMB) m = emb[(size_t)tok[b] * ND + (c0 + c)];
  else     m = multT[(size_t)(c0 + c) * NB + b];
  outT[(size_t)(c0 + c) * NB + b] = g * m;
}

// ---- LSTM gates + state update: one block per hidden column j ----
__global__ __launch_bounds__(256) void lstm_gates(
    const float* __restrict__ xT, const float* __restrict__ hT,
    const float* __restrict__ Wih, const float* __restrict__ Whh,
    const float* __restrict__ bih, const float* __restrict__ bhh,
    float* __restrict__ cT, float* __restrict__ hOut)
{
  const int tid = threadIdx.x;
  const int wv = tid >> 6, lane = tid & 63;
  const int j = blockIdx.x;   // 0..1023
  __shared__ float red[4][8][64];
  float acc[8] = {0.f,0.f,0.f,0.f,0.f,0.f,0.f,0.f};
  const int kb = wv * 256;
  const float* xp = xT + (size_t)kb * NB + lane;
  const float* hp = hT + (size_t)kb * NB + lane;

  for (int k = 0; k < 256; k += 8) {
    float xv[8], hv[8];
#pragma unroll
    for (int q = 0; q < 8; ++q) { xv[q] = xp[(k + q) * NB]; hv[q] = hp[(k + q) * NB]; }
#pragma unroll
    for (int g = 0; g < 4; ++g) {
      const size_t row = (size_t)(g * ND + j) * ND + kb + k;
      acc[g]     = dot8_f32(xv, Wih + row, acc[g]);
      acc[4 + g] = dot8_f32(hv, Whh + row, acc[4 + g]);
    }
  }
#pragma unroll
  for (int g = 0; g < 8; ++g) red[wv][g][lane] = acc[g];
  __syncthreads();

  if (tid < NB) {
    const int b = tid;
    float pre[4];
#pragma unroll
    for (int g = 0; g < 4; ++g) {
      float s = 0.f;
#pragma unroll
      for (int w = 0; w < 4; ++w) s += red[w][g][b] + red[w][4 + g][b];
      pre[g] = s + bih[g * ND + j] + bhh[g * ND + j];
    }
    float iv = sigf(pre[0]), fv = sigf(pre[1]);
    float gv = tanhf(pre[2]), ov = sigf(pre[3]);
    float cn = fv * cT[(size_t)j * NB + b] + iv * gv;
    float hn = ov * tanhf(cn);
    cT[(size_t)j * NB + b] = cn;
    hOut[(size_t)j * NB + b] = hn;
  }
}

// ---- decoder: one block per 4 vocab columns, f32 out [b][v] ----
__global__ __launch_bounds__(256) void decode_k(
    const float* __restrict__ hT,
    const float* __restrict__ W,      // V x D
    const float* __restrict__ decb,
    float* __restrict__ out)          // + t*B*V
{
  const int tid = threadIdx.x;
  const int wv = tid >> 6, lane = tid & 63;
  const int v0 = blockIdx.x * 4;
  __shared__ float red[4][4][64];
  float acc[4] = {0.f, 0.f, 0.f, 0.f};
  const int kb = wv * 256;
  const float* hp = hT + (size_t)kb * NB + lane;

  for (int k = 0; k < 256; k += 8) {
    float hv[8];
#pragma unroll
    for (int q = 0; q < 8; ++q) hv[q] = hp[(k + q) * NB];
#pragma unroll
    for (int c = 0; c < 4; ++c)
      acc[c] = dot8_f32(hv, W + (size_t)(v0 + c) * ND + kb + k, acc[c]);
  }
#pragma unroll
  for (int c = 0; c < 4; ++c) red[wv][c][lane] = acc[c];
  __syncthreads();

  const int c = tid >> 6, b = tid & 63;
  float z = red[0][c][b] + red[1][c][b] + red[2][c][b] + red[3][c][b];
  z += decb[v0 + c];
  out[(size_t)b * NV + v0 + c] = z;
}

__global__ void finalize(const float* __restrict__ hT, const float* __restrict__ cT,
                         float* __restrict__ out) {
  int i = blockIdx.x * 256 + threadIdx.x;  // 0..65535
  int k = i >> 6, b = i & 63;
  size_t base = (size_t)SEQ_LEN * NB * NV;
  out[base + (size_t)b * ND + k] = hT[i];
  out[base + (size_t)NB * ND + (size_t)b * ND + k] = cT[i];
}

extern "C" void kernel_launch(void* const* d_in, const int* in_sizes, int n_in,
                              void* d_out, int out_size, void* d_ws, size_t ws_size,
                              hipStream_t stream)
{
  float* out = (float*)d_out;
  const unsigned long long expect_out = (unsigned long long)SEQ_LEN * NB * NV + 2ull * NB * ND;

  auto flood = [&](float v) {
    unsigned long long n = (unsigned long long)out_size;
    unsigned int g = (unsigned int)((n + 255) / 256);
    floodk<<<g, 256, 0, stream>>>(out, v, n);
  };
  const int expect_sz[14] = {
    SEQ_LEN * NB, NV * ND, 2 * ND * ND, 2 * ND, 2 * ND * ND, 2 * ND,
    4 * ND * ND, 4 * ND * ND, 4 * ND, 4 * ND, NV * ND, NV, NB * ND, NB * ND };
  if (n_in != 14) { flood(1000.f); return; }
  for (int i = 0; i < 14; ++i)
    if (in_sizes[i] != expect_sz[i]) { flood(1100.f + 100.f * i); return; }
  if ((unsigned long long)out_size != expect_out) { flood(2500.f); return; }

  float* ws = (float*)d_ws;
  const size_t SB = (size_t)ND * NB;   // 65536
  if (ws_size < 7 * SB * sizeof(float)) { flood(2600.f); return; }

  const int*   tokens = (const int*)d_in[0];
  const float* emb  = (const float*)d_in[1];
  const float* qw   = (const float*)d_in[2];
  const float* qb   = (const float*)d_in[3];
  const float* rw   = (const float*)d_in[4];
  const float* rb   = (const float*)d_in[5];
  const float* wih  = (const float*)d_in[6];
  const float* whh  = (const float*)d_in[7];
  const float* bih  = (const float*)d_in[8];
  const float* bhh  = (const float*)d_in[9];
  const float* decw = (const float*)d_in[10];
  const float* decb = (const float*)d_in[11];
  const float* h0   = (const float*)d_in[12];
  const float* c0   = (const float*)d_in[13];

  float* xA = ws + 0 * SB;
  float* xB = ws + 1 * SB;
  float* h1 = ws + 2 * SB;
  float* h3 = ws + 3 * SB;
  float* hP = ws + 4 * SB;
  float* hQ = ws + 5 * SB;
  float* cS = ws + 6 * SB;

  const size_t DH = (size_t)ND * ND;

  init_state<<<256, 256, 0, stream>>>(h0, c0, hP, cS);
  float* hc = hP;
  float* hn = hQ;
  for (int t = 0; t < SEQ_LEN; ++t) {
    const int* tk = tokens + (size_t)t * NB;
    // r=0: x = 2*sig(h@qw0^T + qb0) * emb[tok]
    mog_phase<true ><<<256, 256, 0, stream>>>(hc, qw, qb, nullptr, emb, tk, xA);
    // r=0: h = 2*sig(x@rw0^T + rb0) * h
    mog_phase<false><<<256, 256, 0, stream>>>(xA, rw, rb, hc, nullptr, nullptr, h1);
    // r=1: x = 2*sig(h@qw1^T + qb1) * x
    mog_phase<false><<<256, 256, 0, stream>>>(h1, qw + DH, qb + ND, xA, nullptr, nullptr, xB);
    // r=1: h = 2*sig(x@rw1^T + rb1) * h
    mog_phase<false><<<256, 256, 0, stream>>>(xB, rw + DH, rb + ND, h1, nullptr, nullptr, h3);
    // LSTM cell
    lstm_gates<<<1024, 256, 0, stream>>>(xB, h3, wih, whh, bih, bhh, cS, hn);
    // decode
    decode_k<<<2500, 256, 0, stream>>>(hn, decw, decb, out + (size_t)t * NB * NV);
    float* tmp = hc; hc = hn; hn = tmp;
  }
  finalize<<<256, 256, 0, stream>>>(hc, cS, out);
}

// Round 5
// 41503.513 us; speedup vs baseline: 1.4065x; 1.4065x over previous
//
#include <hip/hip_runtime.h>
#include <hip/hip_bf16.h>

#define SEQ_LEN 256
#define NB 64
#define NV 10000
#define ND 1024

__device__ __forceinline__ float sigf(float z) { return 1.f / (1.f + expf(-z)); }

__device__ __forceinline__ float dot8_f32(const float* hv, const float* wp, float acc) {
  float4 w0 = *(const float4*)wp;
  float4 w1 = *(const float4*)(wp + 4);
  acc += hv[0] * w0.x; acc += hv[1] * w0.y; acc += hv[2] * w0.z; acc += hv[3] * w0.w;
  acc += hv[4] * w1.x; acc += hv[5] * w1.y; acc += hv[6] * w1.z; acc += hv[7] * w1.w;
  return acc;
}

// ---- diagnostic flood (f32 out) ----
__global__ void floodk(float* out, float val, unsigned long long n) {
  unsigned long long i = (unsigned long long)blockIdx.x * 256 + threadIdx.x;
  if (i < n) out[i] = val;
}

// ---- init: transpose f32 states to feature-major [k][b] ----
__global__ void init_state(const float* __restrict__ h0, const float* __restrict__ c0,
                           float* __restrict__ hT, float* __restrict__ cT) {
  int i = blockIdx.x * 256 + threadIdx.x;   // 0..65535
  int k = i >> 6, b = i & 63;
  hT[i] = h0[b * ND + k];
  cT[i] = c0[b * ND + k];
}

// ---- mogrifier phase ----
template<bool EMB>
__global__ __launch_bounds__(256) void mog_phase(
    const float* __restrict__ actT,   // 1024 x 64 feature-major
    const float* __restrict__ W,      // C x 1024 row-major
    const float* __restrict__ bias,   // C
    const float* __restrict__ multT,  // C x 64 (if !EMB)
    const float* __restrict__ emb,    // V x D  (if EMB)
    const int*   __restrict__ tok,    // B      (if EMB)
    float* __restrict__ outT)         // C x 64
{
  const int tid = threadIdx.x;
  const int wv = tid >> 6;
  const int lane = tid & 63;
  const int c0 = blockIdx.x * 4;
  __shared__ float red[4][4][64];

  float acc[4] = {0.f, 0.f, 0.f, 0.f};
  const int kb = wv * 256;
  const float* ap = actT + (size_t)kb * NB + lane;

  for (int k = 0; k < 256; k += 8) {
    float hv[8];
#pragma unroll
    for (int q = 0; q < 8; ++q) hv[q] = ap[(k + q) * NB];
#pragma unroll
    for (int c = 0; c < 4; ++c)
      acc[c] = dot8_f32(hv, W + (size_t)(c0 + c) * ND + kb + k, acc[c]);
  }
#pragma unroll
  for (int c = 0; c < 4; ++c) red[wv][c][lane] = acc[c];
  __syncthreads();

  const int c = tid >> 6, b = tid & 63;
  float z = red[0][c][b] + red[1][c][b] + red[2][c][b] + red[3][c][b];
  z += bias[c0 + c];
  float g = 2.f * sigf(z);
  float m;
  if (EMB) m = emb[(size_t)tok[b] * ND + (c0 + c)];
  else     m = multT[(size_t)(c0 + c) * NB + b];
  outT[(size_t)(c0 + c) * NB + b] = g * m;
}

// ---- LSTM gates + state update: 2 hidden columns per block (grid 512) ----
__global__ __launch_bounds__(256) void lstm_gates2(
    const float* __restrict__ xT, const float* __restrict__ hT,
    const float* __restrict__ Wih, const float* __restrict__ Whh,
    const float* __restrict__ bih, const float* __restrict__ bhh,
    float* __restrict__ cT, float* __restrict__ hOut)
{
  const int tid = threadIdx.x;
  const int wv = tid >> 6, lane = tid & 63;
  const int j0 = blockIdx.x * 2;   // 0..1022
  __shared__ float red[4][16][64];
  float acc[16];
#pragma unroll
  for (int i = 0; i < 16; ++i) acc[i] = 0.f;
  const int kb = wv * 256;
  const float* xp = xT + (size_t)kb * NB + lane;
  const float* hp = hT + (size_t)kb * NB + lane;

  for (int k = 0; k < 256; k += 8) {
    float xv[8], hv[8];
#pragma unroll
    for (int q = 0; q < 8; ++q) { xv[q] = xp[(k + q) * NB]; hv[q] = hp[(k + q) * NB]; }
#pragma unroll
    for (int jj = 0; jj < 2; ++jj) {
#pragma unroll
      for (int g = 0; g < 4; ++g) {
        const size_t row = (size_t)(g * ND + j0 + jj) * ND + kb + k;
        acc[jj * 8 + g]     = dot8_f32(xv, Wih + row, acc[jj * 8 + g]);
        acc[jj * 8 + 4 + g] = dot8_f32(hv, Whh + row, acc[jj * 8 + 4 + g]);
      }
    }
  }
#pragma unroll
  for (int i = 0; i < 16; ++i) red[wv][i][lane] = acc[i];
  __syncthreads();

  if (tid < 128) {
    const int b = tid & 63, jj = tid >> 6;
    const int j = j0 + jj;
    float pre[4];
#pragma unroll
    for (int g = 0; g < 4; ++g) {
      float s = 0.f;
#pragma unroll
      for (int w = 0; w < 4; ++w) s += red[w][jj * 8 + g][b] + red[w][jj * 8 + 4 + g][b];
      pre[g] = s + bih[g * ND + j] + bhh[g * ND + j];
    }
    float iv = sigf(pre[0]), fv = sigf(pre[1]);
    float gv = tanhf(pre[2]), ov = sigf(pre[3]);
    float cn = fv * cT[(size_t)j * NB + b] + iv * gv;
    float hn = ov * tanhf(cn);
    cT[(size_t)j * NB + b] = cn;
    hOut[(size_t)j * NB + b] = hn;
  }
}

// ---- per-step decoder (fallback path only) ----
__global__ __launch_bounds__(256) void decode_k(
    const float* __restrict__ hT,
    const float* __restrict__ W,
    const float* __restrict__ decb,
    float* __restrict__ out)
{
  const int tid = threadIdx.x;
  const int wv = tid >> 6, lane = tid & 63;
  const int v0 = blockIdx.x * 4;
  __shared__ float red[4][4][64];
  float acc[4] = {0.f, 0.f, 0.f, 0.f};
  const int kb = wv * 256;
  const float* hp = hT + (size_t)kb * NB + lane;

  for (int k = 0; k < 256; k += 8) {
    float hv[8];
#pragma unroll
    for (int q = 0; q < 8; ++q) hv[q] = hp[(k + q) * NB];
#pragma unroll
    for (int c = 0; c < 4; ++c)
      acc[c] = dot8_f32(hv, W + (size_t)(v0 + c) * ND + kb + k, acc[c]);
  }
#pragma unroll
  for (int c = 0; c < 4; ++c) red[wv][c][lane] = acc[c];
  __syncthreads();

  const int c = tid >> 6, b = tid & 63;
  float z = red[0][c][b] + red[1][c][b] + red[2][c][b] + red[3][c][b];
  z += decb[v0 + c];
  out[(size_t)b * NV + v0 + c] = z;
}

// ---- batched decode GEMM over the whole h-history ----
// C[t][b][n] = sum_k H[t][k][b] * W[n][k] + bias[n]
// tiles: BM=64 (one t, all b), BN=64, BK=32; block 256 thr, 4x4 acc/thread.
__global__ __launch_bounds__(256) void decode_gemm(
    const float* __restrict__ A,      // hHist+SB: [t][k][b]
    const float* __restrict__ Bw,     // decw: [n][k]
    const float* __restrict__ bias,   // decb
    float* __restrict__ C)            // out: [t][b][n]
{
  const int tid = threadIdx.x;
  const int bid = blockIdx.x;
  const int mt = bid & 255;          // t
  const int nt = bid >> 8;           // 0..156
  const int n0 = nt * 64;

  __shared__ float As[2048];         // [kk][b] flat
  __shared__ float Bs[2048];         // [kk][n] swizzled

  const int tm = tid >> 4, tn = tid & 15;
  float acc[4][4] = {{0.f}};
  const float* Abase = A + (size_t)mt * (ND * NB);

  for (int k0 = 0; k0 < ND; k0 += 32) {
    __syncthreads();
    // A tile: 2048 consecutive floats (rows k contiguous in [k][b] layout)
    {
      const float4* src = (const float4*)(Abase + (size_t)k0 * NB);
      ((float4*)As)[tid] = src[tid];
      ((float4*)As)[tid + 256] = src[tid + 256];
    }
    // B tile: 64 n-rows x 32 k, transpose into Bs[k][n] with XOR swizzle
#pragma unroll
    for (int i = 0; i < 2; ++i) {
      int f = tid + i * 256;          // 0..511
      int n = f >> 3;                 // 0..63
      int kc = f & 7;
      int gn = n0 + n;
      float4 v = make_float4(0.f, 0.f, 0.f, 0.f);
      if (gn < NV) v = *(const float4*)(Bw + (size_t)gn * ND + k0 + kc * 4);
      int k = kc * 4;
      int n4 = n >> 2, nr = n & 3;
      Bs[(k + 0) * 64 + ((n4 ^ ((k + 0) & 7)) << 2) + nr] = v.x;
      Bs[(k + 1) * 64 + ((n4 ^ ((k + 1) & 7)) << 2) + nr] = v.y;
      Bs[(k + 2) * 64 + ((n4 ^ ((k + 2) & 7)) << 2) + nr] = v.z;
      Bs[(k + 3) * 64 + ((n4 ^ ((k + 3) & 7)) << 2) + nr] = v.w;
    }
    __syncthreads();
#pragma unroll
    for (int kk = 0; kk < 32; ++kk) {
      float a4[4], b4[4];
      *(float4*)a4 = *(const float4*)(As + kk * 64 + tm * 4);
      *(float4*)b4 = *(const float4*)(Bs + kk * 64 + ((tn ^ (kk & 7)) << 2));
#pragma unroll
      for (int i = 0; i < 4; ++i)
#pragma unroll
        for (int j = 0; j < 4; ++j)
          acc[i][j] = fmaf(a4[i], b4[j], acc[i][j]);
    }
  }

  // epilogue
  const int nb = n0 + tn * 4;
  float db[4];
#pragma unroll
  for (int j = 0; j < 4; ++j) db[j] = (nb + j < NV) ? bias[nb + j] : 0.f;
  float* Crow = C + (size_t)mt * ((size_t)NB * NV);
#pragma unroll
  for (int i = 0; i < 4; ++i) {
    const int b = tm * 4 + i;
    float* cp = Crow + (size_t)b * NV + nb;
    if (nb + 3 < NV) {
      float4 v;
      v.x = acc[i][0] + db[0]; v.y = acc[i][1] + db[1];
      v.z = acc[i][2] + db[2]; v.w = acc[i][3] + db[3];
      *(float4*)cp = v;
    } else {
#pragma unroll
      for (int j = 0; j < 4; ++j)
        if (nb + j < NV) cp[j] = acc[i][j] + db[j];
    }
  }
}

__global__ void finalize(const float* __restrict__ hT, const float* __restrict__ cT,
                         float* __restrict__ out) {
  int i = blockIdx.x * 256 + threadIdx.x;  // 0..65535
  int k = i >> 6, b = i & 63;
  size_t base = (size_t)SEQ_LEN * NB * NV;
  out[base + (size_t)b * ND + k] = hT[i];
  out[base + (size_t)NB * ND + (size_t)b * ND + k] = cT[i];
}

extern "C" void kernel_launch(void* const* d_in, const int* in_sizes, int n_in,
                              void* d_out, int out_size, void* d_ws, size_t ws_size,
                              hipStream_t stream)
{
  float* out = (float*)d_out;
  const unsigned long long expect_out = (unsigned long long)SEQ_LEN * NB * NV + 2ull * NB * ND;

  auto flood = [&](float v) {
    unsigned long long n = (unsigned long long)out_size;
    unsigned int g = (unsigned int)((n + 255) / 256);
    floodk<<<g, 256, 0, stream>>>(out, v, n);
  };
  const int expect_sz[14] = {
    SEQ_LEN * NB, NV * ND, 2 * ND * ND, 2 * ND, 2 * ND * ND, 2 * ND,
    4 * ND * ND, 4 * ND * ND, 4 * ND, 4 * ND, NV * ND, NV, NB * ND, NB * ND };
  if (n_in != 14) { flood(1000.f); return; }
  for (int i = 0; i < 14; ++i)
    if (in_sizes[i] != expect_sz[i]) { flood(1100.f + 100.f * i); return; }
  if ((unsigned long long)out_size != expect_out) { flood(2500.f); return; }

  float* ws = (float*)d_ws;
  const size_t SB = (size_t)ND * NB;   // 65536
  if (ws_size < 7 * SB * sizeof(float)) { flood(2600.f); return; }

  const int*   tokens = (const int*)d_in[0];
  const float* emb  = (const float*)d_in[1];
  const float* qw   = (const float*)d_in[2];
  const float* qb   = (const float*)d_in[3];
  const float* rw   = (const float*)d_in[4];
  const float* rb   = (const float*)d_in[5];
  const float* wih  = (const float*)d_in[6];
  const float* whh  = (const float*)d_in[7];
  const float* bih  = (const float*)d_in[8];
  const float* bhh  = (const float*)d_in[9];
  const float* decw = (const float*)d_in[10];
  const float* decb = (const float*)d_in[11];
  const float* h0   = (const float*)d_in[12];
  const float* c0   = (const float*)d_in[13];

  float* xA = ws + 0 * SB;
  float* xB = ws + 1 * SB;
  float* h1 = ws + 2 * SB;
  float* h3 = ws + 3 * SB;
  float* cS = ws + 4 * SB;
  float* hHist = ws + 5 * SB;          // up to 257 slots

  const size_t DH = (size_t)ND * ND;
  const bool big = ws_size >= (5 + (size_t)SEQ_LEN + 1) * SB * sizeof(float);

  if (big) {
    init_state<<<256, 256, 0, stream>>>(h0, c0, hHist, cS);
    for (int t = 0; t < SEQ_LEN; ++t) {
      const int* tk = tokens + (size_t)t * NB;
      float* hc = hHist + (size_t)t * SB;
      float* hn = hc + SB;
      mog_phase<true ><<<256, 256, 0, stream>>>(hc, qw, qb, nullptr, emb, tk, xA);
      mog_phase<false><<<256, 256, 0, stream>>>(xA, rw, rb, hc, nullptr, nullptr, h1);
      mog_phase<false><<<256, 256, 0, stream>>>(h1, qw + DH, qb + ND, xA, nullptr, nullptr, xB);
      mog_phase<false><<<256, 256, 0, stream>>>(xB, rw + DH, rb + ND, h1, nullptr, nullptr, h3);
      lstm_gates2<<<512, 256, 0, stream>>>(xB, h3, wih, whh, bih, bhh, cS, hn);
    }
    decode_gemm<<<157 * 256, 256, 0, stream>>>(hHist + SB, decw, decb, out);
    finalize<<<256, 256, 0, stream>>>(hHist + (size_t)SEQ_LEN * SB, cS, out);
  } else {
    // fallback: 2-slot h double-buffer + per-step decode
    float* hA = hHist;
    float* hB = hHist + SB;
    init_state<<<256, 256, 0, stream>>>(h0, c0, hA, cS);
    float* hc = hA;
    float* hn = hB;
    for (int t = 0; t < SEQ_LEN; ++t) {
      const int* tk = tokens + (size_t)t * NB;
      mog_phase<true ><<<256, 256, 0, stream>>>(hc, qw, qb, nullptr, emb, tk, xA);
      mog_phase<false><<<256, 256, 0, stream>>>(xA, rw, rb, hc, nullptr, nullptr, h1);
      mog_phase<false><<<256, 256, 0, stream>>>(h1, qw + DH, qb + ND, xA, nullptr, nullptr, xB);
      mog_phase<false><<<256, 256, 0, stream>>>(xB, rw + DH, rb + ND, h1, nullptr, nullptr, h3);
      lstm_gates2<<<512, 256, 0, stream>>>(xB, h3, wih, whh, bih, bhh, cS, hn);
      decode_k<<<2500, 256, 0, stream>>>(hn, decw, decb, out + (size_t)t * NB * NV);
      float* tmp = hc; hc = hn; hn = tmp;
    }
    finalize<<<256, 256, 0, stream>>>(hc, cS, out);
  }
}